// Round 4
// baseline (103.675 us; speedup 1.0000x reference)
//
#include <hip/hip_runtime.h>

typedef __attribute__((ext_vector_type(4))) float f32x4;
typedef __attribute__((ext_vector_type(8))) short s16x8;
typedef __attribute__((ext_vector_type(4))) short s16x4;
typedef __attribute__((ext_vector_type(8))) __bf16 bf16x8;

#define B_ 64
#define LQ_ 32
#define LP_ 256
#define H_ 768
#define D_ 128

__device__ __forceinline__ short cvt_bf16(float f) {
  unsigned u = __builtin_bit_cast(unsigned, f);
  unsigned r = (u + 0x7fffu + ((u >> 16) & 1u)) >> 16;
  return (short)r;
}
__device__ __forceinline__ float frombf(short h) {
  unsigned v = ((unsigned)(unsigned short)h) << 16;
  return __builtin_bit_cast(float, v);
}
__device__ __forceinline__ f32x4 mfma16(s16x8 a, s16x8 b, f32x4 c) {
  return __builtin_amdgcn_mfma_f32_16x16x32_bf16(
      __builtin_bit_cast(bf16x8, a), __builtin_bit_cast(bf16x8, b), c, 0, 0, 0);
}
__device__ __forceinline__ s16x8 cvt8(f32x4 a, f32x4 b) {
  s16x8 r;
  r[0] = __builtin_bit_cast(short, (__bf16)a[0]);
  r[1] = __builtin_bit_cast(short, (__bf16)a[1]);
  r[2] = __builtin_bit_cast(short, (__bf16)a[2]);
  r[3] = __builtin_bit_cast(short, (__bf16)a[3]);
  r[4] = __builtin_bit_cast(short, (__bf16)b[0]);
  r[5] = __builtin_bit_cast(short, (__bf16)b[1]);
  r[6] = __builtin_bit_cast(short, (__bf16)b[2]);
  r[7] = __builtin_bit_cast(short, (__bf16)b[3]);
  return r;
}

// ---------------- K1: fused pre-work ----------------
// blocks 0..95: W [768][128] f32 -> Wt [128][768] bf16 ; blocks 96..159: masks -> f32
__global__ __launch_bounds__(256) void k_pre(const float* __restrict__ W,
                                             const int* __restrict__ pm,
                                             const int* __restrict__ nm,
                                             short* __restrict__ Wt,
                                             float* __restrict__ mf) {
  __shared__ float tile[32][33];
  int bid = blockIdx.x;
  int t = threadIdx.x;
  if (bid < 96) {
    int k0 = (bid % 24) * 32, n0 = (bid / 24) * 32;
    int r = t >> 3, c4 = (t & 7) << 2;
    f32x4 v = *(const f32x4*)(W + (size_t)(k0 + r) * D_ + n0 + c4);
    tile[r][c4 + 0] = v[0]; tile[r][c4 + 1] = v[1];
    tile[r][c4 + 2] = v[2]; tile[r][c4 + 3] = v[3];
    __syncthreads();
    s16x4 o;
    o[0] = cvt_bf16(tile[c4 + 0][r]);
    o[1] = cvt_bf16(tile[c4 + 1][r]);
    o[2] = cvt_bf16(tile[c4 + 2][r]);
    o[3] = cvt_bf16(tile[c4 + 3][r]);
    *(s16x4*)(Wt + (size_t)(n0 + r) * H_ + k0 + c4) = o;
  } else {
    int i = (bid - 96) * 256 + t;
    float ninf = -__builtin_inff();
    mf[i]         = pm[i] ? 0.f : ninf;
    mf[16384 + i] = nm[i] ? 0.f : ninf;
  }
}

// ---------------- K2: projection GEMM, wave-per-16-rows, no LDS, no barriers --------
// 2176 single-wave blocks. Wave: 16 rows x 128 cols, ni=8, BK=32, 24 iters.
// A (H, f32) direct from global/L3; B (Wt, bf16, 192 KB) direct from L2.
__global__ __launch_bounds__(64) void k_proj(
    const float* __restrict__ Hq, const float* __restrict__ Hp, const float* __restrict__ Hn,
    const short* __restrict__ Wt, const float* __restrict__ bias,
    short* __restrict__ Xq, short* __restrict__ Xp, short* __restrict__ Xn,
    float* __restrict__ ps) {
  int g = blockIdx.x;
  const float* Hs; short* X; int row0;
  if (g < 128)       { Hs = Hq; X = Xq; row0 = g * 16; }
  else if (g < 1152) { Hs = Hp; X = Xp; row0 = (g - 128) * 16; }
  else               { Hs = Hn; X = Xn; row0 = (g - 1152) * 16; }
  int lane = threadIdx.x;
  int lhi = lane >> 4, llo = lane & 15;

  const float* aptr = Hs + (size_t)(row0 + llo) * H_ + lhi * 8;
  const short* bptr = Wt + (size_t)llo * H_ + lhi * 8;

  f32x4 acc[8] = {};
  // prefetch iter 0
  f32x4 pa0 = *(const f32x4*)(aptr);
  f32x4 pa1 = *(const f32x4*)(aptr + 4);
  s16x8 pb[8];
  for (int ni = 0; ni < 8; ni++)
    pb[ni] = *(const s16x8*)(bptr + (size_t)ni * 16 * H_);

  for (int it = 0; it < 24; ++it) {
    s16x8 af = cvt8(pa0, pa1);
    s16x8 bq[8];
    for (int ni = 0; ni < 8; ni++) bq[ni] = pb[ni];
    if (it < 23) {  // issue next-iter loads; overlap with MFMAs below
      const float* ap = aptr + (it + 1) * 32;
      pa0 = *(const f32x4*)(ap);
      pa1 = *(const f32x4*)(ap + 4);
      const short* bp = bptr + (it + 1) * 32;
      for (int ni = 0; ni < 8; ni++)
        pb[ni] = *(const s16x8*)(bp + (size_t)ni * 16 * H_);
    }
    for (int ni = 0; ni < 8; ni++) acc[ni] = mfma16(af, bq[ni], acc[ni]);
  }

  // epilogue: bias, bf16 X write, per-wave (16-row) column sumsq -> ps[g]
  for (int ni = 0; ni < 8; ni++) {
    int col = ni * 16 + llo;
    float bv = bias[col];
    float s = 0.f;
    for (int r = 0; r < 4; r++) {
      float xv = acc[ni][r] + bv;
      s += xv * xv;
      X[(size_t)(row0 + lhi * 4 + r) * D_ + col] = cvt_bf16(xv);
    }
    s += __shfl_xor(s, 16, 64);
    s += __shfl_xor(s, 32, 64);
    if (lhi == 0) ps[(size_t)g * 128 + col] = s;
  }
}

// ---------------- K3: finalize norm + write bf16 V ----------------
// 1088 blocks of 32 rows; ps is in 16-row units (2176 x 128).
__global__ __launch_bounds__(256) void k_normfin(
    const short* __restrict__ Xq, const short* __restrict__ Xp, const short* __restrict__ Xn,
    const float* __restrict__ ps,
    short* __restrict__ Vq, short* __restrict__ Vp, short* __restrict__ Vn) {
  __shared__ float invs[128];
  int bid = blockIdx.x;
  const short* X; short* V; int row0, pbase, pcnt;
  if (bid < 64)       { X = Xq; V = Vq; row0 = bid * 32;         pbase = bid * 2;                         pcnt = 2;  }
  else if (bid < 576) { X = Xp; V = Vp; row0 = (bid - 64) * 32;  pbase = 128 + ((bid - 64) / 8) * 16;     pcnt = 16; }
  else                { X = Xn; V = Vn; row0 = (bid - 576) * 32; pbase = 1152 + ((bid - 576) / 8) * 16;   pcnt = 16; }
  int t = threadIdx.x;
  if (t < 128) {
    float s = 0.f;
    for (int j = 0; j < pcnt; j++) s += ps[(size_t)(pbase + j) * 128 + t];
    invs[t] = 1.0f / fmaxf(sqrtf(s), 1e-12f);
  }
  __syncthreads();
  int row = row0 + (t >> 3), c0 = (t & 7) << 4;
  const short* xr = X + (size_t)row * D_ + c0;
  s16x8 x0 = *(const s16x8*)(xr);
  s16x8 x1 = *(const s16x8*)(xr + 8);
  f32x4 i0 = *(const f32x4*)(&invs[c0]);
  f32x4 i1 = *(const f32x4*)(&invs[c0 + 4]);
  f32x4 i2 = *(const f32x4*)(&invs[c0 + 8]);
  f32x4 i3 = *(const f32x4*)(&invs[c0 + 12]);
  s16x8 o0, o1;
  for (int j = 0; j < 4; j++) {
    o0[j]     = cvt_bf16(frombf(x0[j])     * i0[j]);
    o0[j + 4] = cvt_bf16(frombf(x0[j + 4]) * i1[j]);
    o1[j]     = cvt_bf16(frombf(x1[j])     * i2[j]);
    o1[j + 4] = cvt_bf16(frombf(x1[j + 4]) * i3[j]);
  }
  short* vr = V + (size_t)row * D_ + c0;
  *(s16x8*)(vr) = o0;
  *(s16x8*)(vr + 8) = o1;
}

// ---------------- K4: MaxSim, swapped operands (P=A in LDS, Q=B in regs) ----------------
// grid (64 c, 2 side, 4 q-quarter), 512 thr (8 waves). Wave owns 64 q-rows x all 256 p.
__global__ __launch_bounds__(512, 2) void k_maxsim(
    const short* __restrict__ QV, const short* __restrict__ PV, const short* __restrict__ NV,
    const float* __restrict__ MF, float* __restrict__ OUT) {
  __shared__ short Ps[LP_ * D_];  // 64 KB, XOR-swizzled (pitch 256 B)
  int t = threadIdx.x, lane = t & 63, w = t >> 6;
  int lhi = lane >> 4, llo = lane & 15;
  int c = blockIdx.x, side = blockIdx.y, quarter = blockIdx.z;
  const short* P = side ? NV : PV;
  const float* mfb = MF + (size_t)(side * B_ + c) * LP_;

  const short* qb = QV + (size_t)(quarter * 512 + w * 64) * D_;
  s16x8 bq[4][4];
  for (int ni = 0; ni < 4; ni++)
    for (int ks = 0; ks < 4; ks++)
      bq[ni][ks] = *(const s16x8*)(qb + (size_t)(ni * 16 + llo) * D_ + ks * 32 + lhi * 8);

  const short* src = P + (size_t)c * LP_ * D_;
  for (int i = 0; i < 8; i++) {
    int s = i * 512 + t;
    int p = s >> 4, kc = s & 15;
    s16x8 v = *(const s16x8*)(src + (size_t)p * D_ + kc * 8);
    int byteoff = (p * 256 + kc * 16) ^ ((p & 7) << 4);
    *(s16x8*)((char*)Ps + byteoff) = v;
  }
  __syncthreads();

  float ninf = -__builtin_inff();
  float rmax[4] = {ninf, ninf, ninf, ninf};
  for (int pi = 0; pi < 4; pi++) {
    f32x4 acc[4][4] = {};  // [mi][ni]
    for (int ks = 0; ks < 4; ks++) {
      s16x8 pa[4];
      for (int mi = 0; mi < 4; mi++) {
        int prow = pi * 64 + mi * 16 + llo;
        int off = (prow * 256 + ks * 64 + lhi * 16) ^ ((prow & 7) << 4);
        pa[mi] = *(const s16x8*)((char*)Ps + off);
      }
      __builtin_amdgcn_s_setprio(1);
      for (int mi = 0; mi < 4; mi++)
        for (int ni = 0; ni < 4; ni++)
          acc[mi][ni] = mfma16(pa[mi], bq[ni][ks], acc[mi][ni]);
      __builtin_amdgcn_s_setprio(0);
    }
    f32x4 mk[4];
    for (int mi = 0; mi < 4; mi++)
      mk[mi] = *(const f32x4*)(mfb + pi * 64 + mi * 16 + lhi * 4);
    for (int ni = 0; ni < 4; ni++)
      for (int mi = 0; mi < 4; mi++)
        for (int r = 0; r < 4; r++)
          rmax[ni] = fmaxf(rmax[ni], acc[mi][ni][r] + mk[mi][r]);
  }
  for (int ni = 0; ni < 4; ni++) {
    rmax[ni] = fmaxf(rmax[ni], __shfl_xor(rmax[ni], 16, 64));
    rmax[ni] = fmaxf(rmax[ni], __shfl_xor(rmax[ni], 32, 64));
  }
  float s0 = rmax[0] + rmax[1];
  float s1 = rmax[2] + rmax[3];
  for (int m = 1; m < 16; m <<= 1) {
    s0 += __shfl_xor(s0, m, 64);
    s1 += __shfl_xor(s1, m, 64);
  }
  if (lane == 0) {
    int b0 = quarter * 16 + w * 2;
    OUT[(size_t)b0 * 128 + side * 64 + c] = s0;
    OUT[(size_t)(b0 + 1) * 128 + side * 64 + c] = s1;
  }
}

extern "C" void kernel_launch(void* const* d_in, const int* in_sizes, int n_in,
                              void* d_out, int out_size, void* d_ws, size_t ws_size,
                              hipStream_t stream) {
  const float* qh = (const float*)d_in[0];
  const float* ph = (const float*)d_in[1];
  const float* nh = (const float*)d_in[2];
  const float* W  = (const float*)d_in[3];
  const float* bias = (const float*)d_in[4];
  const int* pm = (const int*)d_in[5];
  const int* nm = (const int*)d_in[6];
  float* out = (float*)d_out;
  char* ws = (char*)d_ws;

  short* Wt = (short*)(ws + 0x0);        // 128x768 bf16      192 KB
  float* mf = (float*)(ws + 0x30000);    // 2x64x256 f32      128 KB
  float* ps = (float*)(ws + 0x50000);    // 2176x128 f32      1.09 MB
  short* xq = (short*)(ws + 0x160000);   // 2048x128 bf16     512 KB
  short* xp = (short*)(ws + 0x1E0000);   // 16384x128 bf16    4 MB
  short* xn = (short*)(ws + 0x5E0000);   // 16384x128 bf16    4 MB
  short* qv = (short*)(ws + 0x9E0000);   // 2048x128 bf16     512 KB
  short* pv = (short*)(ws + 0xA60000);   // 16384x128 bf16    4 MB
  short* nv = (short*)(ws + 0xE60000);   // 16384x128 bf16    4 MB

  k_pre<<<160, 256, 0, stream>>>(W, pm, nm, Wt, mf);
  k_proj<<<2176, 64, 0, stream>>>(qh, ph, nh, Wt, bias, xq, xp, xn, ps);
  k_normfin<<<1088, 256, 0, stream>>>(xq, xp, xn, ps, qv, pv, nv);
  k_maxsim<<<dim3(64, 2, 4), 512, 0, stream>>>(qv, pv, nv, mf, out);
}

// Round 5
// 92.577 us; speedup vs baseline: 1.1199x; 1.1199x over previous
//
#include <hip/hip_runtime.h>

typedef __attribute__((ext_vector_type(4))) float f32x4;
typedef __attribute__((ext_vector_type(8))) short s16x8;
typedef __attribute__((ext_vector_type(4))) short s16x4;
typedef __attribute__((ext_vector_type(8))) __bf16 bf16x8;

#define B_ 64
#define LQ_ 32
#define LP_ 256
#define H_ 768
#define D_ 128

__device__ __forceinline__ short cvt_bf16(float f) {
  unsigned u = __builtin_bit_cast(unsigned, f);
  unsigned r = (u + 0x7fffu + ((u >> 16) & 1u)) >> 16;
  return (short)r;
}
__device__ __forceinline__ float frombf(short h) {
  unsigned v = ((unsigned)(unsigned short)h) << 16;
  return __builtin_bit_cast(float, v);
}
__device__ __forceinline__ f32x4 mfma16(s16x8 a, s16x8 b, f32x4 c) {
  return __builtin_amdgcn_mfma_f32_16x16x32_bf16(
      __builtin_bit_cast(bf16x8, a), __builtin_bit_cast(bf16x8, b), c, 0, 0, 0);
}
__device__ __forceinline__ s16x8 cvt8(f32x4 a, f32x4 b) {
  s16x8 r;
  r[0] = __builtin_bit_cast(short, (__bf16)a[0]);
  r[1] = __builtin_bit_cast(short, (__bf16)a[1]);
  r[2] = __builtin_bit_cast(short, (__bf16)a[2]);
  r[3] = __builtin_bit_cast(short, (__bf16)a[3]);
  r[4] = __builtin_bit_cast(short, (__bf16)b[0]);
  r[5] = __builtin_bit_cast(short, (__bf16)b[1]);
  r[6] = __builtin_bit_cast(short, (__bf16)b[2]);
  r[7] = __builtin_bit_cast(short, (__bf16)b[3]);
  return r;
}

// ---------------- K1: fused pre-work ----------------
__global__ __launch_bounds__(256) void k_pre(const float* __restrict__ W,
                                             const int* __restrict__ pm,
                                             const int* __restrict__ nm,
                                             short* __restrict__ Wt,
                                             float* __restrict__ mf) {
  __shared__ float tile[32][33];
  int bid = blockIdx.x;
  int t = threadIdx.x;
  if (bid < 96) {
    int k0 = (bid % 24) * 32, n0 = (bid / 24) * 32;
    int r = t >> 3, c4 = (t & 7) << 2;
    f32x4 v = *(const f32x4*)(W + (size_t)(k0 + r) * D_ + n0 + c4);
    tile[r][c4 + 0] = v[0]; tile[r][c4 + 1] = v[1];
    tile[r][c4 + 2] = v[2]; tile[r][c4 + 3] = v[3];
    __syncthreads();
    s16x4 o;
    o[0] = cvt_bf16(tile[c4 + 0][r]);
    o[1] = cvt_bf16(tile[c4 + 1][r]);
    o[2] = cvt_bf16(tile[c4 + 2][r]);
    o[3] = cvt_bf16(tile[c4 + 3][r]);
    *(s16x4*)(Wt + (size_t)(n0 + r) * H_ + k0 + c4) = o;
  } else {
    int i = (bid - 96) * 256 + t;
    float ninf = -__builtin_inff();
    mf[i]         = pm[i] ? 0.f : ninf;
    mf[16384 + i] = nm[i] ? 0.f : ninf;
  }
}

// ---------------- K2: projection GEMM, K-split waves + static 2-deep pipeline ----
// 1088 blocks x 256 thr. Block = 32 rows. Wave (ch,kh): cols ch*64..+63, K-half kh.
// 12 iters of BK=32, 8 loads/iter, all buffer indices compile-time constant.
__global__ __launch_bounds__(256, 4) void k_proj(
    const float* __restrict__ Hq, const float* __restrict__ Hp, const float* __restrict__ Hn,
    const short* __restrict__ Wt, const float* __restrict__ bias,
    short* __restrict__ Xq, short* __restrict__ Xp, short* __restrict__ Xn,
    float* __restrict__ ps) {
  __shared__ float sm[32 * 128];  // 16 KB K-half exchange
  int bid = blockIdx.x;
  const float* Hs; short* X; int row0;
  if (bid < 64)       { Hs = Hq; X = Xq; row0 = bid * 32; }
  else if (bid < 576) { Hs = Hp; X = Xp; row0 = (bid - 64) * 32; }
  else                { Hs = Hn; X = Xn; row0 = (bid - 576) * 32; }
  int t = threadIdx.x, lane = t & 63, w = t >> 6;
  int ch = w & 1, kh = w >> 1;
  int lhi = lane >> 4, llo = lane & 15;
  int kbase = kh * 384;

  const float* a0p = Hs + (size_t)(row0 + llo) * H_ + kbase + lhi * 8;
  const float* a1p = a0p + (size_t)16 * H_;
  const short* bp0 = Wt + (size_t)(ch * 64 + llo) * H_ + kbase + lhi * 8;
  const short* bp1 = bp0 + (size_t)16 * H_;
  const short* bp2 = bp0 + (size_t)32 * H_;
  const short* bp3 = bp0 + (size_t)48 * H_;

  f32x4 paA[2][2][2];
  s16x8 pbB[2][4];
  // preload it=0 -> slot0, it=1 -> slot1 (A stride 32 f32/iter, B 32 bf16/iter)
  paA[0][0][0] = *(const f32x4*)(a0p);      paA[0][0][1] = *(const f32x4*)(a0p + 4);
  paA[0][1][0] = *(const f32x4*)(a1p);      paA[0][1][1] = *(const f32x4*)(a1p + 4);
  pbB[0][0] = *(const s16x8*)(bp0);
  pbB[0][1] = *(const s16x8*)(bp1);
  pbB[0][2] = *(const s16x8*)(bp2);
  pbB[0][3] = *(const s16x8*)(bp3);
  paA[1][0][0] = *(const f32x4*)(a0p + 32); paA[1][0][1] = *(const f32x4*)(a0p + 36);
  paA[1][1][0] = *(const f32x4*)(a1p + 32); paA[1][1][1] = *(const f32x4*)(a1p + 36);
  pbB[1][0] = *(const s16x8*)(bp0 + 32);
  pbB[1][1] = *(const s16x8*)(bp1 + 32);
  pbB[1][2] = *(const s16x8*)(bp2 + 32);
  pbB[1][3] = *(const s16x8*)(bp3 + 32);

  f32x4 acc[2][4] = {};

#define PSTEP(S, NXT, RELOAD)                                            \
  {                                                                      \
    s16x8 af0 = cvt8(paA[S][0][0], paA[S][0][1]);                        \
    s16x8 af1 = cvt8(paA[S][1][0], paA[S][1][1]);                        \
    if (RELOAD) {                                                        \
      paA[S][0][0] = *(const f32x4*)(a0p + (NXT) * 32);                  \
      paA[S][0][1] = *(const f32x4*)(a0p + (NXT) * 32 + 4);              \
      paA[S][1][0] = *(const f32x4*)(a1p + (NXT) * 32);                  \
      paA[S][1][1] = *(const f32x4*)(a1p + (NXT) * 32 + 4);              \
    }                                                                    \
    acc[0][0] = mfma16(af0, pbB[S][0], acc[0][0]);                       \
    acc[0][1] = mfma16(af0, pbB[S][1], acc[0][1]);                       \
    acc[0][2] = mfma16(af0, pbB[S][2], acc[0][2]);                       \
    acc[0][3] = mfma16(af0, pbB[S][3], acc[0][3]);                       \
    acc[1][0] = mfma16(af1, pbB[S][0], acc[1][0]);                       \
    acc[1][1] = mfma16(af1, pbB[S][1], acc[1][1]);                       \
    acc[1][2] = mfma16(af1, pbB[S][2], acc[1][2]);                       \
    acc[1][3] = mfma16(af1, pbB[S][3], acc[1][3]);                       \
    if (RELOAD) {                                                        \
      pbB[S][0] = *(const s16x8*)(bp0 + (NXT) * 32);                     \
      pbB[S][1] = *(const s16x8*)(bp1 + (NXT) * 32);                     \
      pbB[S][2] = *(const s16x8*)(bp2 + (NXT) * 32);                     \
      pbB[S][3] = *(const s16x8*)(bp3 + (NXT) * 32);                     \
    }                                                                    \
  }

  PSTEP(0, 2, 1)  PSTEP(1, 3, 1)  PSTEP(0, 4, 1)  PSTEP(1, 5, 1)
  PSTEP(0, 6, 1)  PSTEP(1, 7, 1)  PSTEP(0, 8, 1)  PSTEP(1, 9, 1)
  PSTEP(0, 10, 1) PSTEP(1, 11, 1) PSTEP(0, 0, 0)  PSTEP(1, 0, 0)
#undef PSTEP

  // merge K-halves via LDS, then epilogue on kh=0 waves
  if (kh == 1) {
    for (int mi = 0; mi < 2; mi++)
      for (int ni = 0; ni < 4; ni++)
        for (int r = 0; r < 4; r++)
          sm[(mi * 16 + lhi * 4 + r) * 128 + ch * 64 + ni * 16 + llo] = acc[mi][ni][r];
  }
  __syncthreads();
  if (kh == 0) {
    for (int ni = 0; ni < 4; ni++) {
      int col = ch * 64 + ni * 16 + llo;
      float bv = bias[col];
      float s = 0.f;
      for (int mi = 0; mi < 2; mi++) {
        for (int r = 0; r < 4; r++) {
          int m = mi * 16 + lhi * 4 + r;
          float xv = acc[mi][ni][r] + sm[m * 128 + col] + bv;
          s += xv * xv;
          X[(size_t)(row0 + m) * D_ + col] = cvt_bf16(xv);
        }
      }
      s += __shfl_xor(s, 16, 64);
      s += __shfl_xor(s, 32, 64);
      if (lhi == 0) ps[(size_t)bid * 128 + col] = s;
    }
  }
}

// ---------------- K3: finalize norm + write bf16 V ----------------
// 1088 blocks of 32 rows; ps in 32-row units (1088 x 128), unit == bid.
__global__ __launch_bounds__(256) void k_normfin(
    const short* __restrict__ Xq, const short* __restrict__ Xp, const short* __restrict__ Xn,
    const float* __restrict__ ps,
    short* __restrict__ Vq, short* __restrict__ Vp, short* __restrict__ Vn) {
  __shared__ float invs[128];
  int bid = blockIdx.x;
  const short* X; short* V; int row0, pbase, pcnt;
  if (bid < 64)       { X = Xq; V = Vq; row0 = bid * 32;         pbase = bid;                        pcnt = 1; }
  else if (bid < 576) { X = Xp; V = Vp; row0 = (bid - 64) * 32;  pbase = 64 + ((bid - 64) & ~7);     pcnt = 8; }
  else                { X = Xn; V = Vn; row0 = (bid - 576) * 32; pbase = 576 + ((bid - 576) & ~7);   pcnt = 8; }
  int t = threadIdx.x;
  if (t < 128) {
    float s = 0.f;
    for (int j = 0; j < pcnt; j++) s += ps[(size_t)(pbase + j) * 128 + t];
    invs[t] = 1.0f / fmaxf(sqrtf(s), 1e-12f);
  }
  __syncthreads();
  int row = row0 + (t >> 3), c0 = (t & 7) << 4;
  const short* xr = X + (size_t)row * D_ + c0;
  s16x8 x0 = *(const s16x8*)(xr);
  s16x8 x1 = *(const s16x8*)(xr + 8);
  f32x4 i0 = *(const f32x4*)(&invs[c0]);
  f32x4 i1 = *(const f32x4*)(&invs[c0 + 4]);
  f32x4 i2 = *(const f32x4*)(&invs[c0 + 8]);
  f32x4 i3 = *(const f32x4*)(&invs[c0 + 12]);
  s16x8 o0, o1;
  for (int j = 0; j < 4; j++) {
    o0[j]     = cvt_bf16(frombf(x0[j])     * i0[j]);
    o0[j + 4] = cvt_bf16(frombf(x0[j + 4]) * i1[j]);
    o1[j]     = cvt_bf16(frombf(x1[j])     * i2[j]);
    o1[j + 4] = cvt_bf16(frombf(x1[j + 4]) * i3[j]);
  }
  short* vr = V + (size_t)row * D_ + c0;
  *(s16x8*)(vr) = o0;
  *(s16x8*)(vr + 8) = o1;
}

// ---------------- K4: MaxSim, swapped operands (P=A in LDS, Q=B in regs) ----------------
__global__ __launch_bounds__(512, 2) void k_maxsim(
    const short* __restrict__ QV, const short* __restrict__ PV, const short* __restrict__ NV,
    const float* __restrict__ MF, float* __restrict__ OUT) {
  __shared__ short Ps[LP_ * D_];  // 64 KB, XOR-swizzled (pitch 256 B)
  int t = threadIdx.x, lane = t & 63, w = t >> 6;
  int lhi = lane >> 4, llo = lane & 15;
  int c = blockIdx.x, side = blockIdx.y, quarter = blockIdx.z;
  const short* P = side ? NV : PV;
  const float* mfb = MF + (size_t)(side * B_ + c) * LP_;

  const short* qb = QV + (size_t)(quarter * 512 + w * 64) * D_;
  s16x8 bq[4][4];
  for (int ni = 0; ni < 4; ni++)
    for (int ks = 0; ks < 4; ks++)
      bq[ni][ks] = *(const s16x8*)(qb + (size_t)(ni * 16 + llo) * D_ + ks * 32 + lhi * 8);

  const short* src = P + (size_t)c * LP_ * D_;
  for (int i = 0; i < 8; i++) {
    int s = i * 512 + t;
    int p = s >> 4, kc = s & 15;
    s16x8 v = *(const s16x8*)(src + (size_t)p * D_ + kc * 8);
    int byteoff = (p * 256 + kc * 16) ^ ((p & 7) << 4);
    *(s16x8*)((char*)Ps + byteoff) = v;
  }
  __syncthreads();

  float ninf = -__builtin_inff();
  float rmax[4] = {ninf, ninf, ninf, ninf};
  for (int pi = 0; pi < 4; pi++) {
    f32x4 acc[4][4] = {};  // [mi][ni]
    for (int ks = 0; ks < 4; ks++) {
      s16x8 pa[4];
      for (int mi = 0; mi < 4; mi++) {
        int prow = pi * 64 + mi * 16 + llo;
        int off = (prow * 256 + ks * 64 + lhi * 16) ^ ((prow & 7) << 4);
        pa[mi] = *(const s16x8*)((char*)Ps + off);
      }
      __builtin_amdgcn_s_setprio(1);
      for (int mi = 0; mi < 4; mi++)
        for (int ni = 0; ni < 4; ni++)
          acc[mi][ni] = mfma16(pa[mi], bq[ni][ks], acc[mi][ni]);
      __builtin_amdgcn_s_setprio(0);
    }
    f32x4 mk[4];
    for (int mi = 0; mi < 4; mi++)
      mk[mi] = *(const f32x4*)(mfb + pi * 64 + mi * 16 + lhi * 4);
    for (int ni = 0; ni < 4; ni++)
      for (int mi = 0; mi < 4; mi++)
        for (int r = 0; r < 4; r++)
          rmax[ni] = fmaxf(rmax[ni], acc[mi][ni][r] + mk[mi][r]);
  }
  for (int ni = 0; ni < 4; ni++) {
    rmax[ni] = fmaxf(rmax[ni], __shfl_xor(rmax[ni], 16, 64));
    rmax[ni] = fmaxf(rmax[ni], __shfl_xor(rmax[ni], 32, 64));
  }
  float s0 = rmax[0] + rmax[1];
  float s1 = rmax[2] + rmax[3];
  for (int m = 1; m < 16; m <<= 1) {
    s0 += __shfl_xor(s0, m, 64);
    s1 += __shfl_xor(s1, m, 64);
  }
  if (lane == 0) {
    int b0 = quarter * 16 + w * 2;
    OUT[(size_t)b0 * 128 + side * 64 + c] = s0;
    OUT[(size_t)(b0 + 1) * 128 + side * 64 + c] = s1;
  }
}

extern "C" void kernel_launch(void* const* d_in, const int* in_sizes, int n_in,
                              void* d_out, int out_size, void* d_ws, size_t ws_size,
                              hipStream_t stream) {
  const float* qh = (const float*)d_in[0];
  const float* ph = (const float*)d_in[1];
  const float* nh = (const float*)d_in[2];
  const float* W  = (const float*)d_in[3];
  const float* bias = (const float*)d_in[4];
  const int* pm = (const int*)d_in[5];
  const int* nm = (const int*)d_in[6];
  float* out = (float*)d_out;
  char* ws = (char*)d_ws;

  short* Wt = (short*)(ws + 0x0);        // 128x768 bf16      192 KB
  float* mf = (float*)(ws + 0x30000);    // 2x64x256 f32      128 KB
  float* ps = (float*)(ws + 0x50000);    // 1088x128 f32      557 KB
  short* xq = (short*)(ws + 0x160000);   // 2048x128 bf16     512 KB
  short* xp = (short*)(ws + 0x1E0000);   // 16384x128 bf16    4 MB
  short* xn = (short*)(ws + 0x5E0000);   // 16384x128 bf16    4 MB
  short* qv = (short*)(ws + 0x9E0000);   // 2048x128 bf16     512 KB
  short* pv = (short*)(ws + 0xA60000);   // 16384x128 bf16    4 MB
  short* nv = (short*)(ws + 0xE60000);   // 16384x128 bf16    4 MB

  k_pre<<<160, 256, 0, stream>>>(W, pm, nm, Wt, mf);
  k_proj<<<1088, 256, 0, stream>>>(qh, ph, nh, Wt, bias, xq, xp, xn, ps);
  k_normfin<<<1088, 256, 0, stream>>>(xq, xp, xn, ps, qv, pv, nv);
  k_maxsim<<<dim3(64, 2, 4), 512, 0, stream>>>(qv, pv, nv, mf, out);
}

// Round 6
// 65.350 us; speedup vs baseline: 1.5865x; 1.4166x over previous
//
#include <hip/hip_runtime.h>

typedef __attribute__((ext_vector_type(4))) float f32x4;
typedef __attribute__((ext_vector_type(8))) short s16x8;
typedef __attribute__((ext_vector_type(4))) short s16x4;
typedef __attribute__((ext_vector_type(8))) __bf16 bf16x8;

#define B_ 64
#define LQ_ 32
#define LP_ 256
#define H_ 768
#define D_ 128

__device__ __forceinline__ short cvt_bf16(float f) {
  unsigned u = __builtin_bit_cast(unsigned, f);
  unsigned r = (u + 0x7fffu + ((u >> 16) & 1u)) >> 16;
  return (short)r;
}
__device__ __forceinline__ float frombf(short h) {
  unsigned v = ((unsigned)(unsigned short)h) << 16;
  return __builtin_bit_cast(float, v);
}
__device__ __forceinline__ f32x4 mfma16(s16x8 a, s16x8 b, f32x4 c) {
  return __builtin_amdgcn_mfma_f32_16x16x32_bf16(
      __builtin_bit_cast(bf16x8, a), __builtin_bit_cast(bf16x8, b), c, 0, 0, 0);
}
__device__ __forceinline__ s16x8 cvt8(f32x4 a, f32x4 b) {
  s16x8 r;
  r[0] = __builtin_bit_cast(short, (__bf16)a[0]);
  r[1] = __builtin_bit_cast(short, (__bf16)a[1]);
  r[2] = __builtin_bit_cast(short, (__bf16)a[2]);
  r[3] = __builtin_bit_cast(short, (__bf16)a[3]);
  r[4] = __builtin_bit_cast(short, (__bf16)b[0]);
  r[5] = __builtin_bit_cast(short, (__bf16)b[1]);
  r[6] = __builtin_bit_cast(short, (__bf16)b[2]);
  r[7] = __builtin_bit_cast(short, (__bf16)b[3]);
  return r;
}
// async global -> LDS DMA, 16 B per lane, dest = wave-uniform base + lane*16
__device__ __forceinline__ void gload16(const void* g, void* l) {
  __builtin_amdgcn_global_load_lds(
      (const __attribute__((address_space(1))) void*)g,
      (__attribute__((address_space(3))) void*)l, 16, 0, 0);
}

// ---------------- K1: fused pre-work ----------------
__global__ __launch_bounds__(256) void k_pre(const float* __restrict__ W,
                                             const int* __restrict__ pm,
                                             const int* __restrict__ nm,
                                             short* __restrict__ Wt,
                                             float* __restrict__ mf) {
  __shared__ float tile[32][33];
  int bid = blockIdx.x;
  int t = threadIdx.x;
  if (bid < 96) {
    int k0 = (bid % 24) * 32, n0 = (bid / 24) * 32;
    int r = t >> 3, c4 = (t & 7) << 2;
    f32x4 v = *(const f32x4*)(W + (size_t)(k0 + r) * D_ + n0 + c4);
    tile[r][c4 + 0] = v[0]; tile[r][c4 + 1] = v[1];
    tile[r][c4 + 2] = v[2]; tile[r][c4 + 3] = v[3];
    __syncthreads();
    s16x4 o;
    o[0] = cvt_bf16(tile[c4 + 0][r]);
    o[1] = cvt_bf16(tile[c4 + 1][r]);
    o[2] = cvt_bf16(tile[c4 + 2][r]);
    o[3] = cvt_bf16(tile[c4 + 3][r]);
    *(s16x4*)(Wt + (size_t)(n0 + r) * H_ + k0 + c4) = o;
  } else {
    int i = (bid - 96) * 256 + t;
    float ninf = -__builtin_inff();
    mf[i]         = pm[i] ? 0.f : ninf;
    mf[16384 + i] = nm[i] ? 0.f : ninf;
  }
}

// ---------------- K2: projection GEMM via global_load_lds 2-phase double-buffer ----
// 1088 blocks x 256 thr. Block = 32 rows x 128 cols, BK=32, 24 iters.
// Wave w: rows (w&1)*16..+15, cols (w>>1)*64..+63. acc = f32x4[4].
// LDS per buffer: A 4 KB (f32, source-swizzled) + B 8 KB (bf16, source-swizzled).
__global__ __launch_bounds__(256, 6) void k_proj(
    const float* __restrict__ Hq, const float* __restrict__ Hp, const float* __restrict__ Hn,
    const short* __restrict__ Wt, const float* __restrict__ bias,
    short* __restrict__ Xq, short* __restrict__ Xp, short* __restrict__ Xn,
    float* __restrict__ ps) {
  __shared__ __attribute__((aligned(128))) char smem[2 * 12288 + 1024];
  float* psum = (float*)(smem + 24576);
  int bid = blockIdx.x;
  const float* Hs; short* X; int row0;
  if (bid < 64)       { Hs = Hq; X = Xq; row0 = bid * 32; }
  else if (bid < 576) { Hs = Hp; X = Xp; row0 = (bid - 64) * 32; }
  else                { Hs = Hn; X = Xn; row0 = (bid - 576) * 32; }
  int t = threadIdx.x, lane = t & 63, w = t >> 6;
  int wm = w & 1, wc = w >> 1;
  int lhi = lane >> 4, llo = lane & 15;

  // ---- staging: per-lane global source (inverse-swizzled), linear LDS dest ----
  // A: instr per wave covers rows w*8 .. w*8+7, 8 granules (16 B = 4 f32) per row.
  int arow_s = w * 8 + (lane >> 3);
  int ag     = (lane & 7) ^ (lane >> 3);           // g_src = g_dest ^ (row&7)
  const float* asrc = Hs + (size_t)(row0 + arow_s) * H_ + ag * 4;
  // B: instrs 2w, 2w+1 cover rows i*16 .. i*16+15, 4 granules per row.
  int brow0_s = (2 * w) * 16 + (lane >> 2);
  int brow1_s = (2 * w + 1) * 16 + (lane >> 2);
  int bg = (lane & 3) ^ ((lane >> 3) & 3);          // g_src = g_dest ^ ((row>>1)&3)
  const short* bsrc0 = Wt + (size_t)brow0_s * H_ + bg * 8;
  const short* bsrc1 = Wt + (size_t)brow1_s * H_ + bg * 8;

  // ---- fragment read byte offsets within a buffer (swizzled reads) ----
  int arow = wm * 16 + llo;
  int aoff0 = arow * 128 + ((lhi * 2) ^ (arow & 7)) * 16;
  int aoff1 = arow * 128 + ((lhi * 2 + 1) ^ (arow & 7)) * 16;
  int boff[4];
  for (int ni = 0; ni < 4; ni++) {
    int br = wc * 64 + ni * 16 + llo;
    boff[ni] = 4096 + br * 64 + (lhi ^ ((br >> 1) & 3)) * 16;
  }

#define STAGE(buf, kelems)                                                \
  {                                                                       \
    char* base_ = smem + (buf) * 12288;                                   \
    gload16(asrc + (kelems), base_ + w * 1024);                           \
    gload16(bsrc0 + (kelems), base_ + 4096 + (2 * w) * 1024);             \
    gload16(bsrc1 + (kelems), base_ + 4096 + (2 * w + 1) * 1024);         \
  }

  STAGE(0, 0)
  __syncthreads();

  f32x4 acc[4] = {};
  for (int it = 0; it < 24; ++it) {
    int cur = it & 1;
    if (it < 23) STAGE(cur ^ 1, (it + 1) * 32)
    char* cb = smem + cur * 12288;
    f32x4 a0 = *(const f32x4*)(cb + aoff0);
    f32x4 a1 = *(const f32x4*)(cb + aoff1);
    s16x8 af = cvt8(a0, a1);
    s16x8 bf0 = *(const s16x8*)(cb + boff[0]);
    s16x8 bf1 = *(const s16x8*)(cb + boff[1]);
    s16x8 bf2 = *(const s16x8*)(cb + boff[2]);
    s16x8 bf3 = *(const s16x8*)(cb + boff[3]);
    acc[0] = mfma16(af, bf0, acc[0]);
    acc[1] = mfma16(af, bf1, acc[1]);
    acc[2] = mfma16(af, bf2, acc[2]);
    acc[3] = mfma16(af, bf3, acc[3]);
    __syncthreads();  // drains this wave's 3 DMA loads + LDS reads, flips buffer
  }
#undef STAGE

  // epilogue: bias, bf16 X write, block column-sumsq partials
  for (int ni = 0; ni < 4; ni++) {
    int col = wc * 64 + ni * 16 + llo;
    float bv = bias[col];
    float s = 0.f;
    for (int r = 0; r < 4; r++) {
      float xv = acc[ni][r] + bv;
      s += xv * xv;
      X[(size_t)(row0 + wm * 16 + lhi * 4 + r) * D_ + col] = cvt_bf16(xv);
    }
    s += __shfl_xor(s, 16, 64);
    s += __shfl_xor(s, 32, 64);
    if (lhi == 0) psum[wm * 128 + col] = s;
  }
  __syncthreads();
  if (t < 128) ps[(size_t)bid * 128 + t] = psum[t] + psum[128 + t];
}

// ---------------- K3: finalize norm + write bf16 V ----------------
// 1088 blocks of 32 rows; ps in 32-row units (1088 x 128), unit == bid.
__global__ __launch_bounds__(256) void k_normfin(
    const short* __restrict__ Xq, const short* __restrict__ Xp, const short* __restrict__ Xn,
    const float* __restrict__ ps,
    short* __restrict__ Vq, short* __restrict__ Vp, short* __restrict__ Vn) {
  __shared__ float invs[128];
  int bid = blockIdx.x;
  const short* X; short* V; int row0, pbase, pcnt;
  if (bid < 64)       { X = Xq; V = Vq; row0 = bid * 32;         pbase = bid;                        pcnt = 1; }
  else if (bid < 576) { X = Xp; V = Vp; row0 = (bid - 64) * 32;  pbase = 64 + ((bid - 64) & ~7);     pcnt = 8; }
  else                { X = Xn; V = Vn; row0 = (bid - 576) * 32; pbase = 576 + ((bid - 576) & ~7);   pcnt = 8; }
  int t = threadIdx.x;
  if (t < 128) {
    float s = 0.f;
    for (int j = 0; j < pcnt; j++) s += ps[(size_t)(pbase + j) * 128 + t];
    invs[t] = 1.0f / fmaxf(sqrtf(s), 1e-12f);
  }
  __syncthreads();
  int row = row0 + (t >> 3), c0 = (t & 7) << 4;
  const short* xr = X + (size_t)row * D_ + c0;
  s16x8 x0 = *(const s16x8*)(xr);
  s16x8 x1 = *(const s16x8*)(xr + 8);
  f32x4 i0 = *(const f32x4*)(&invs[c0]);
  f32x4 i1 = *(const f32x4*)(&invs[c0 + 4]);
  f32x4 i2 = *(const f32x4*)(&invs[c0 + 8]);
  f32x4 i3 = *(const f32x4*)(&invs[c0 + 12]);
  s16x8 o0, o1;
  for (int j = 0; j < 4; j++) {
    o0[j]     = cvt_bf16(frombf(x0[j])     * i0[j]);
    o0[j + 4] = cvt_bf16(frombf(x0[j + 4]) * i1[j]);
    o1[j]     = cvt_bf16(frombf(x1[j])     * i2[j]);
    o1[j + 4] = cvt_bf16(frombf(x1[j + 4]) * i3[j]);
  }
  short* vr = V + (size_t)row * D_ + c0;
  *(s16x8*)(vr) = o0;
  *(s16x8*)(vr + 8) = o1;
}

// ---------------- K4: MaxSim, swapped operands (P=A in LDS, Q=B in regs) ----------------
__global__ __launch_bounds__(512, 2) void k_maxsim(
    const short* __restrict__ QV, const short* __restrict__ PV, const short* __restrict__ NV,
    const float* __restrict__ MF, float* __restrict__ OUT) {
  __shared__ short Ps[LP_ * D_];  // 64 KB, XOR-swizzled (pitch 256 B)
  int t = threadIdx.x, lane = t & 63, w = t >> 6;
  int lhi = lane >> 4, llo = lane & 15;
  int c = blockIdx.x, side = blockIdx.y, quarter = blockIdx.z;
  const short* P = side ? NV : PV;
  const float* mfb = MF + (size_t)(side * B_ + c) * LP_;

  const short* qb = QV + (size_t)(quarter * 512 + w * 64) * D_;
  s16x8 bq[4][4];
  for (int ni = 0; ni < 4; ni++)
    for (int ks = 0; ks < 4; ks++)
      bq[ni][ks] = *(const s16x8*)(qb + (size_t)(ni * 16 + llo) * D_ + ks * 32 + lhi * 8);

  const short* src = P + (size_t)c * LP_ * D_;
  for (int i = 0; i < 8; i++) {
    int s = i * 512 + t;
    int p = s >> 4, kc = s & 15;
    s16x8 v = *(const s16x8*)(src + (size_t)p * D_ + kc * 8);
    int byteoff = (p * 256 + kc * 16) ^ ((p & 7) << 4);
    *(s16x8*)((char*)Ps + byteoff) = v;
  }
  __syncthreads();

  float ninf = -__builtin_inff();
  float rmax[4] = {ninf, ninf, ninf, ninf};
  for (int pi = 0; pi < 4; pi++) {
    f32x4 acc[4][4] = {};  // [mi][ni]
    for (int ks = 0; ks < 4; ks++) {
      s16x8 pa[4];
      for (int mi = 0; mi < 4; mi++) {
        int prow = pi * 64 + mi * 16 + llo;
        int off = (prow * 256 + ks * 64 + lhi * 16) ^ ((prow & 7) << 4);
        pa[mi] = *(const s16x8*)((char*)Ps + off);
      }
      __builtin_amdgcn_s_setprio(1);
      for (int mi = 0; mi < 4; mi++)
        for (int ni = 0; ni < 4; ni++)
          acc[mi][ni] = mfma16(pa[mi], bq[ni][ks], acc[mi][ni]);
      __builtin_amdgcn_s_setprio(0);
    }
    f32x4 mk[4];
    for (int mi = 0; mi < 4; mi++)
      mk[mi] = *(const f32x4*)(mfb + pi * 64 + mi * 16 + lhi * 4);
    for (int ni = 0; ni < 4; ni++)
      for (int mi = 0; mi < 4; mi++)
        for (int r = 0; r < 4; r++)
          rmax[ni] = fmaxf(rmax[ni], acc[mi][ni][r] + mk[mi][r]);
  }
  for (int ni = 0; ni < 4; ni++) {
    rmax[ni] = fmaxf(rmax[ni], __shfl_xor(rmax[ni], 16, 64));
    rmax[ni] = fmaxf(rmax[ni], __shfl_xor(rmax[ni], 32, 64));
  }
  float s0 = rmax[0] + rmax[1];
  float s1 = rmax[2] + rmax[3];
  for (int m = 1; m < 16; m <<= 1) {
    s0 += __shfl_xor(s0, m, 64);
    s1 += __shfl_xor(s1, m, 64);
  }
  if (lane == 0) {
    int b0 = quarter * 16 + w * 2;
    OUT[(size_t)b0 * 128 + side * 64 + c] = s0;
    OUT[(size_t)(b0 + 1) * 128 + side * 64 + c] = s1;
  }
}

extern "C" void kernel_launch(void* const* d_in, const int* in_sizes, int n_in,
                              void* d_out, int out_size, void* d_ws, size_t ws_size,
                              hipStream_t stream) {
  const float* qh = (const float*)d_in[0];
  const float* ph = (const float*)d_in[1];
  const float* nh = (const float*)d_in[2];
  const float* W  = (const float*)d_in[3];
  const float* bias = (const float*)d_in[4];
  const int* pm = (const int*)d_in[5];
  const int* nm = (const int*)d_in[6];
  float* out = (float*)d_out;
  char* ws = (char*)d_ws;

  short* Wt = (short*)(ws + 0x0);        // 128x768 bf16      192 KB
  float* mf = (float*)(ws + 0x30000);    // 2x64x256 f32      128 KB
  float* ps = (float*)(ws + 0x50000);    // 1088x128 f32      557 KB
  short* xq = (short*)(ws + 0x160000);   // 2048x128 bf16     512 KB
  short* xp = (short*)(ws + 0x1E0000);   // 16384x128 bf16    4 MB
  short* xn = (short*)(ws + 0x5E0000);   // 16384x128 bf16    4 MB
  short* qv = (short*)(ws + 0x9E0000);   // 2048x128 bf16     512 KB
  short* pv = (short*)(ws + 0xA60000);   // 16384x128 bf16    4 MB
  short* nv = (short*)(ws + 0xE60000);   // 16384x128 bf16    4 MB

  k_pre<<<160, 256, 0, stream>>>(W, pm, nm, Wt, mf);
  k_proj<<<1088, 256, 0, stream>>>(qh, ph, nh, Wt, bias, xq, xp, xn, ps);
  k_normfin<<<1088, 256, 0, stream>>>(xq, xp, xn, ps, qv, pv, nv);
  k_maxsim<<<dim3(64, 2, 4), 512, 0, stream>>>(qv, pv, nv, mf, out);
}